// Round 7
// baseline (199.409 us; speedup 1.0000x reference)
//
#include <hip/hip_runtime.h>
#include <cstdint>

#define B_ 4
#define S_ 4096
#define D_ 512
#define M_ (B_*S_)   // 16384 rows

typedef _Float16 f16;
typedef _Float16 f16x8 __attribute__((ext_vector_type(8)));
typedef _Float16 f16x4 __attribute__((ext_vector_type(4)));
typedef _Float16 f16x2 __attribute__((ext_vector_type(2)));
typedef float    f32x4 __attribute__((ext_vector_type(4)));

typedef __attribute__((address_space(1))) void* as1p;
typedef __attribute__((address_space(3))) void* as3p;

__device__ __forceinline__ void gl2lds16(const void* g, void* l) {
    __builtin_amdgcn_global_load_lds((as1p)g, (as3p)l, 16, 0, 0);
}

union f16pack { f16x8 v8; f16x2 v2[4]; };

// ---------------- prep_tr: blocks 0..255 = xs cast + column partial sums;
//                  blocks 256..511 = weight transpose/cast to f16 ----------------
__global__ __launch_bounds__(256) void prep_tr_kernel(
    const float* __restrict__ xs,
    const float* __restrict__ Wv, const float* __restrict__ Wk,
    const float* __restrict__ Wq, const float* __restrict__ Wl,
    f16* __restrict__ xs_h, float* __restrict__ partialXS,
    f16* __restrict__ WvT, f16* __restrict__ WkT, f16* __restrict__ WqT,
    f16* __restrict__ WlH)
{
    __shared__ float smem[64*68];   // prep: red[4][512]; tr: tile[64][68]
    const int t = threadIdx.x;
    if (blockIdx.x < 256) {
        const int blk = blockIdx.x;
        const int w = t >> 6, l = t & 63;
        const int col = l * 8;
        float acc[8] = {0,0,0,0,0,0,0,0};
        for (int c = 0; c < 16; c++) {
            int row = blk*64 + c*4 + w;
            const float4* p = (const float4*)(xs + (size_t)row*512 + col);
            float4 a = p[0], b = p[1];
            f16x8 o;
            o[0]=(f16)a.x; o[1]=(f16)a.y; o[2]=(f16)a.z; o[3]=(f16)a.w;
            o[4]=(f16)b.x; o[5]=(f16)b.y; o[6]=(f16)b.z; o[7]=(f16)b.w;
            *(f16x8*)(xs_h + (size_t)row*512 + col) = o;
            acc[0]+=a.x; acc[1]+=a.y; acc[2]+=a.z; acc[3]+=a.w;
            acc[4]+=b.x; acc[5]+=b.y; acc[6]+=b.z; acc[7]+=b.w;
        }
        #pragma unroll
        for (int q = 0; q < 8; q++) smem[w*512 + col + q] = acc[q];
        __syncthreads();
        #pragma unroll
        for (int k = 0; k < 2; k++) {
            int c = t + k*256;
            partialXS[(size_t)blk*512 + c] = smem[c] + smem[512+c] + smem[1024+c] + smem[1536+c];
        }
        return;
    }
    const int v = blockIdx.x - 256;
    const int z = v >> 6, tile_id = v & 63;
    const int bx = tile_id & 7, by = tile_id >> 3;
    if (z == 3) {    // Wl cast (row-major f16)
        const size_t base = (size_t)tile_id*4096 + t*16;
        const float4* s4 = (const float4*)(Wl + base);
        float4 a0 = s4[0], a1 = s4[1], a2 = s4[2], a3 = s4[3];
        f16x8 o0, o1;
        o0[0]=(f16)a0.x; o0[1]=(f16)a0.y; o0[2]=(f16)a0.z; o0[3]=(f16)a0.w;
        o0[4]=(f16)a1.x; o0[5]=(f16)a1.y; o0[6]=(f16)a1.z; o0[7]=(f16)a1.w;
        o1[0]=(f16)a2.x; o1[1]=(f16)a2.y; o1[2]=(f16)a2.z; o1[3]=(f16)a2.w;
        o1[4]=(f16)a3.x; o1[5]=(f16)a3.y; o1[6]=(f16)a3.z; o1[7]=(f16)a3.w;
        *(f16x8*)(WlH + base)     = o0;
        *(f16x8*)(WlH + base + 8) = o1;
        return;
    }
    // transpose tile (row stride 68 floats = 272 B = 17*16 -> float4 stores aligned)
    float (*tile)[68] = (float(*)[68])smem;
    const float* src = (z == 0) ? Wv : ((z == 1) ? Wk : Wq);
    f16* dst = (z == 0) ? WvT : ((z == 1) ? WkT : WqT);
    const int i0 = bx*64, j0 = by*64;
    const int r = t >> 2, cpart = (t & 3)*16;
    {
        const float4* s4 = (const float4*)(src + (size_t)(i0 + r)*512 + j0 + cpart);
        float4 a0 = s4[0], a1 = s4[1], a2 = s4[2], a3 = s4[3];
        *(float4*)&tile[r][cpart]    = a0;
        *(float4*)&tile[r][cpart+4]  = a1;
        *(float4*)&tile[r][cpart+8]  = a2;
        *(float4*)&tile[r][cpart+12] = a3;
    }
    __syncthreads();
    const int c = t >> 2, rpart = (t & 3)*16;
    f16x8 o0, o1;
    #pragma unroll
    for (int q = 0; q < 8; q++) o0[q] = (f16)tile[rpart + q][c];
    #pragma unroll
    for (int q = 0; q < 8; q++) o1[q] = (f16)tile[rpart + 8 + q][c];
    *(f16x8*)(dst + (size_t)(j0 + c)*512 + i0 + rpart)     = o0;
    *(f16x8*)(dst + (size_t)(j0 + c)*512 + i0 + rpart + 8) = o1;
}

// ---------------- wmm: MFMA weight GEMMs (as R6) ----------------
__global__ __launch_bounds__(256) void wmm_kernel(
    const f16* __restrict__ WlH, const f16* __restrict__ WvT,
    const f16* __restrict__ WkT, const f16* __restrict__ WqT,
    const float* __restrict__ Wl, const float* __restrict__ bv,
    const float* __restrict__ bk, const float* __restrict__ bq,
    f16* __restrict__ WvlH, float* __restrict__ bvlG,
    float* __restrict__ Mm, float* __restrict__ MT,
    float* __restrict__ t1, float* __restrict__ t2, float* __restrict__ t12)
{
    __shared__ f16 lA[64*32];
    __shared__ f16 lB[64*32];
    const int t = threadIdx.x, z = blockIdx.z;
    const int i0 = blockIdx.x*64, j0 = blockIdx.y*64;
    const int lane = t & 63, wid = t >> 6;
    const int wm = (wid & 1)*32, wn = (wid >> 1)*32;
    const f16* A = z ? WkT : WlH;
    const f16* B = z ? WqT : WvT;
    const int srow = t >> 2, skb = (t & 3) << 4;
    const long aoff = (long)(i0 + srow)*1024 + skb;
    const long boff = (long)(j0 + srow)*1024 + skb;
    const unsigned wbase = (unsigned)wid << 10;
    const bool doT1 = (z == 1) && (blockIdx.x == 0);
    const bool doT2 = (z == 1) && (blockIdx.y == 0);
    const int jj = t >> 2, kq = (t & 3)*8;

    f32x4 acc[2][2] = {};
    float t1a = 0.f, t2a = 0.f;
    const int ael = (wm + (lane & 15))*32 + ((lane >> 4) << 3);
    const int bel = (wn + (lane & 15))*32 + ((lane >> 4) << 3);

    for (int k0 = 0; k0 < 512; k0 += 32) {
        __syncthreads();
        gl2lds16((const char*)A + aoff + k0*2, (char*)lA + wbase);
        gl2lds16((const char*)B + boff + k0*2, (char*)lB + wbase);
        __syncthreads();
        f16x8 af[2], bf[2];
        af[0] = *(const f16x8*)(lA + ael);
        af[1] = *(const f16x8*)(lA + ael + 512);
        bf[0] = *(const f16x8*)(lB + bel);
        bf[1] = *(const f16x8*)(lB + bel + 512);
        #pragma unroll
        for (int i = 0; i < 2; i++)
            #pragma unroll
            for (int j = 0; j < 2; j++)
                acc[i][j] = __builtin_amdgcn_mfma_f32_16x16x32_f16(af[i], bf[j], acc[i][j], 0, 0, 0);
        if (doT1) {
            float4 b0 = *(const float4*)(bk + k0 + kq);
            float4 b1 = *(const float4*)(bk + k0 + kq + 4);
            float bb[8] = {b0.x,b0.y,b0.z,b0.w,b1.x,b1.y,b1.z,b1.w};
            #pragma unroll
            for (int q = 0; q < 8; q++) t1a += (float)lB[jj*32 + kq + q] * bb[q];
        }
        if (doT2) {
            float4 b0 = *(const float4*)(bq + k0 + kq);
            float4 b1 = *(const float4*)(bq + k0 + kq + 4);
            float bb[8] = {b0.x,b0.y,b0.z,b0.w,b1.x,b1.y,b1.z,b1.w};
            #pragma unroll
            for (int q = 0; q < 8; q++) t2a += (float)lA[jj*32 + kq + q] * bb[q];
        }
    }

    const int rb = wm + ((lane >> 4) << 2);
    const int cb = wn + (lane & 15);
    if (z == 0) {
        #pragma unroll
        for (int i = 0; i < 2; i++)
            #pragma unroll
            for (int j = 0; j < 2; j++)
                #pragma unroll
                for (int r = 0; r < 4; r++)
                    WvlH[(size_t)(i0 + rb + i*16 + r)*512 + j0 + cb + j*16] = (f16)acc[i][j][r];
        if (blockIdx.y == 0) {
            int r = t >> 2, part = t & 3;
            const float4* wr = (const float4*)(Wl + (size_t)(i0+r)*512 + part*128);
            const float4* bp = (const float4*)(bv + part*128);
            float s = 0.f;
            #pragma unroll 8
            for (int q = 0; q < 32; q++) {
                float4 wv4 = wr[q], b4 = bp[q];
                s += wv4.x*b4.x + wv4.y*b4.y + wv4.z*b4.z + wv4.w*b4.w;
            }
            s += __shfl_xor(s, 1);
            s += __shfl_xor(s, 2);
            if (part == 0) bvlG[i0 + r] = s;
        }
    } else {
        #pragma unroll
        for (int i = 0; i < 2; i++)
            #pragma unroll
            for (int j = 0; j < 2; j++)
                #pragma unroll
                for (int r = 0; r < 4; r++) {
                    float v = acc[i][j][r];
                    int row = i0 + rb + i*16 + r, col = j0 + cb + j*16;
                    Mm[(size_t)row*512 + col] = v;
                    MT[(size_t)col*512 + row] = v;
                }
        if (doT1) {
            t1a += __shfl_xor(t1a, 1);
            t1a += __shfl_xor(t1a, 2);
            if ((lane & 3) == 0) t1[j0 + jj] = t1a;
        }
        if (doT2) {
            t2a += __shfl_xor(t2a, 1);
            t2a += __shfl_xor(t2a, 2);
            if ((lane & 3) == 0) t2[i0 + jj] = t2a;
        }
        if (blockIdx.x == 0 && blockIdx.y == 0 && wid == 0) {
            float s = 0.f;
            #pragma unroll
            for (int q = 0; q < 8; q++) s += bk[lane + q*64]*bq[lane + q*64];
            #pragma unroll
            for (int m = 1; m < 64; m <<= 1) s += __shfl_xor(s, m);
            if (lane == 0) *t12 = s;
        }
    }
}

// ---------------- mva: reduce P[256][512] (+PS0) -> vsh/beta, then
// oput[b][j] = W[j,:].vsh[b] + beta_b*bias2[j]; block32: cG[b] = bias3.vsh[b] + beta_b*t12 ----
__global__ __launch_bounds__(256) void mva_kernel(
    const float* __restrict__ P, const float* __restrict__ PS0,
    const float* __restrict__ W, const float* __restrict__ bias2,
    const float* __restrict__ bias3, const float* __restrict__ t12G,
    float* __restrict__ oput, f16* __restrict__ oput_h,
    float* __restrict__ cG, float* __restrict__ S0out)
{
    __shared__ float vsh[4][512];
    __shared__ float beta_sh[4];
    __shared__ float s0red[256];
    const int t = threadIdx.x;
    #pragma unroll
    for (int k = 0; k < 8; k++) {
        int idx = k*256 + t;
        int b = idx >> 9, c = idx & 511;
        const float* p = P + (size_t)(b*64)*512 + c;
        float s = 0.f;
        #pragma unroll 8
        for (int q = 0; q < 64; q++) s += p[(size_t)q*512];
        vsh[b][c] = s;
    }
    if (PS0) s0red[t] = PS0[t];
    __syncthreads();
    if (t < 4) {
        float bsum = 4096.0f;
        if (PS0) {
            float s = 0.f;
            for (int q = 0; q < 64; q++) s += s0red[t*64 + q];
            bsum = s;
            if (blockIdx.x == 32 && S0out) S0out[t] = s;
        }
        beta_sh[t] = bsum;
    }
    __syncthreads();

    const int w = t >> 6, l = t & 63;
    if (blockIdx.x == 32) {      // scalar c per batch (wave = batch)
        float s = 0.f;
        #pragma unroll
        for (int q = 0; q < 8; q++) s += bias3[l*8+q]*vsh[w][l*8+q];
        #pragma unroll
        for (int m = 1; m < 64; m <<= 1) s += __shfl_xor(s, m);
        if (l == 0) cG[w] = s + beta_sh[w]*(*t12G);
        return;
    }
    float vb[4][8];
    #pragma unroll
    for (int b = 0; b < 4; b++) {
        float4 p0 = *(const float4*)&vsh[b][l*8];
        float4 p1 = *(const float4*)&vsh[b][l*8+4];
        vb[b][0]=p0.x; vb[b][1]=p0.y; vb[b][2]=p0.z; vb[b][3]=p0.w;
        vb[b][4]=p1.x; vb[b][5]=p1.y; vb[b][6]=p1.z; vb[b][7]=p1.w;
    }
    const int r0 = blockIdx.x*16 + w*4;
    float res[4][4];
    #pragma unroll
    for (int r = 0; r < 4; r++) {
        const float4* wr = (const float4*)(W + (size_t)(r0+r)*512 + l*8);
        float4 a = wr[0], c = wr[1];
        float wv[8] = {a.x,a.y,a.z,a.w,c.x,c.y,c.z,c.w};
        #pragma unroll
        for (int b = 0; b < 4; b++) {
            float s = 0.f;
            #pragma unroll
            for (int q = 0; q < 8; q++) s += wv[q]*vb[b][q];
            res[r][b] = s;
        }
    }
    #pragma unroll
    for (int r = 0; r < 4; r++)
        #pragma unroll
        for (int b = 0; b < 4; b++)
            #pragma unroll
            for (int m = 1; m < 64; m <<= 1) res[r][b] += __shfl_xor(res[r][b], m);
    if (l < 4) {
        const float beta = beta_sh[l];
        #pragma unroll
        for (int r = 0; r < 4; r++) {
            float val = res[r][l] + beta*bias2[r0 + r];
            if (oput)   oput[l*512 + r0 + r] = val;
            if (oput_h) oput_h[l*512 + r0 + r] = (f16)val;
        }
    }
}

// ---------------- z: iv = 1/(4096 + (xs.h + c1)/512); partialY += iv*xs, partialS0 ----------------
__global__ __launch_bounds__(256) void z_kernel(const f16* __restrict__ xs_h,
    const float* __restrict__ hG, const float* __restrict__ c1G,
    float* __restrict__ partialY, float* __restrict__ partialS0)
{
    __shared__ float hs[512];
    __shared__ float yred[4][512];
    __shared__ float s0red[4];
    const int blk = blockIdx.x, t = threadIdx.x;
    const int b = blk >> 6, w = t >> 6, l = t & 63;
    hs[t] = hG[b*512 + t]; hs[t+256] = hG[b*512 + t + 256];
    __syncthreads();
    const float c1 = c1G[b];
    float hx[8];
    #pragma unroll
    for (int q = 0; q < 8; q++) hx[q] = hs[l*8+q];
    float yacc[8] = {0,0,0,0,0,0,0,0};
    float s0acc = 0.f;
    for (int it = 0; it < 16; it++) {
        int row = blk*64 + w*16 + it;
        f16x8 v = *(const f16x8*)(xs_h + (size_t)row*512 + l*8);
        float xf[8];
        #pragma unroll
        for (int q = 0; q < 8; q++) xf[q] = (float)v[q];
        float d = 0.f;
        #pragma unroll
        for (int q = 0; q < 8; q++) d += xf[q]*hx[q];
        #pragma unroll
        for (int m = 1; m < 64; m <<= 1) d += __shfl_xor(d, m);
        float z  = 4096.0f + (d + c1)*(1.0f/512.0f);
        float iv = 1.0f/z;
        s0acc += iv;
        #pragma unroll
        for (int q = 0; q < 8; q++) yacc[q] += iv*xf[q];
    }
    #pragma unroll
    for (int q = 0; q < 8; q++) yred[w][l*8+q] = yacc[q];
    if (l == 0) s0red[w] = s0acc;
    __syncthreads();
    #pragma unroll
    for (int k = 0; k < 2; k++) {
        int c = t + k*256;
        partialY[(size_t)blk*512 + c] = yred[0][c]+yred[1][c]+yred[2][c]+yred[3][c];
    }
    if (t == 0) partialS0[blk] = s0red[0]+s0red[1]+s0red[2]+s0red[3];
}

// ---------------- vl_gemm: BK=64, XOR-swizzled LDS (conflict-free b128 reads),
//                  u in LDS; out = tanh(rs*(xs@Wvl^T + bvl) + bl) ----------------
__global__ __launch_bounds__(256, 2) void vl_gemm(const f16* __restrict__ A,
    const f16* __restrict__ Bt, const float* __restrict__ bvlG,
    const float* __restrict__ blG, const f16* __restrict__ uH,
    const float* __restrict__ c2G, const float* __restrict__ S0G,
    float* __restrict__ out)
{
    __shared__ f16 lA[128*64];   // 16 KB, row = 128 B, granule g at (g ^ (row&7))
    __shared__ f16 lB[128*64];
    __shared__ f16 uL[512];
    __shared__ float rsbuf[128];
    const int t = threadIdx.x;
    const int m0 = blockIdx.x*128, n0 = blockIdx.y*128;
    const int lane = t & 63, wid = t >> 6;
    const int wm = (wid & 1) << 6, wn = (wid >> 1) << 6;
    const int bat = blockIdx.x >> 5;
    // staging: call c covers LDS bytes c*4096 + t*16 -> row c*32 + (t>>3), stored-granule t&7.
    // stored-granule gg holds source granule gg ^ (row&7); row&7 == (t>>3)&7.
    const int sx = (t & 7) ^ ((t >> 3) & 7);
    const long abase = (long)(m0 + (t >> 3))*1024 + sx*16;
    const long bbase = (long)(n0 + (t >> 3))*1024 + sx*16;
    const char* Ab = (const char*)A;
    const char* Bb = (const char*)Bt;
    const unsigned wbase = (unsigned)wid << 10;

    if (t < 64) *(f16x8*)(uL + t*8) = *(const f16x8*)(uH + bat*512 + t*8);

    f32x4 acc[4][4] = {};
    float racc[4] = {0.f,0.f,0.f,0.f};
    const int ku = (lane >> 4) << 3;

    for (int k0 = 0; k0 < 512; k0 += 64) {
        __syncthreads();
        const long kb = (long)k0*2;
        #pragma unroll
        for (int c = 0; c < 4; c++) {
            gl2lds16(Ab + abase + c*32768 + kb, (char*)lA + c*4096 + wbase);
            gl2lds16(Bb + bbase + c*32768 + kb, (char*)lB + c*4096 + wbase);
        }
        __syncthreads();
        #pragma unroll
        for (int kk2 = 0; kk2 < 2; kk2++) {
            const int g = (lane >> 4) + kk2*4;
            f16x8 af[4], bf[4];
            #pragma unroll
            for (int i = 0; i < 4; i++) {
                int m = wm + (lane & 15) + i*16;
                af[i] = *(const f16x8*)((char*)lA + m*128 + ((g ^ (m & 7)) << 4));
            }
            #pragma unroll
            for (int j = 0; j < 4; j++) {
                int n = wn + (lane & 15) + j*16;
                bf[j] = *(const f16x8*)((char*)lB + n*128 + ((g ^ (n & 7)) << 4));
            }
            f16pack up; up.v8 = *(const f16x8*)(uL + k0 + kk2*32 + ku);
            #pragma unroll
            for (int i = 0; i < 4; i++) {
                f16pack ap; ap.v8 = af[i];
                #pragma unroll
                for (int q = 0; q < 4; q++)
                    racc[i] = __builtin_amdgcn_fdot2(ap.v2[q], up.v2[q], racc[i], false);
            }
            #pragma unroll
            for (int i = 0; i < 4; i++)
                #pragma unroll
                for (int j = 0; j < 4; j++)
                    acc[i][j] = __builtin_amdgcn_mfma_f32_16x16x32_f16(af[i], bf[j], acc[i][j], 0, 0, 0);
        }
    }

    #pragma unroll
    for (int i = 0; i < 4; i++) {
        racc[i] += __shfl_xor(racc[i], 16);
        racc[i] += __shfl_xor(racc[i], 32);
    }
    const float S0 = S0G[bat], c2 = c2G[bat];
    if (wid < 2 && lane < 16) {
        #pragma unroll
        for (int i = 0; i < 4; i++)
            rsbuf[wm + i*16 + lane] = S0 + (racc[i] + c2)*(1.0f/512.0f);
    }
    __syncthreads();

    const int crb = m0 + wm + ((lane >> 4) << 2);
    const int ccb = n0 + wn + (lane & 15);
    const int lrb = wm + ((lane >> 4) << 2);
    #pragma unroll
    for (int i = 0; i < 4; i++) {
        float rsv[4];
        #pragma unroll
        for (int r = 0; r < 4; r++) rsv[r] = rsbuf[lrb + i*16 + r];
        #pragma unroll
        for (int j = 0; j < 4; j++) {
            int c = ccb + j*16;
            float bb = bvlG[c], bo = blG[c];
            #pragma unroll
            for (int r = 0; r < 4; r++) {
                float yv = rsv[r]*(acc[i][j][r] + bb) + bo;
                float e2 = __expf(2.0f*yv);
                out[(size_t)(crb + i*16 + r)*512 + c] = 1.0f - 2.0f/(e2 + 1.0f);
            }
        }
    }
}

extern "C" void kernel_launch(void* const* d_in, const int* in_sizes, int n_in,
                              void* d_out, int out_size, void* d_ws, size_t ws_size,
                              hipStream_t stream)
{
    const float* xs = (const float*)d_in[0];
    const float* Wk = (const float*)d_in[1];
    const float* bk = (const float*)d_in[2];
    const float* Wq = (const float*)d_in[3];
    const float* bq = (const float*)d_in[4];
    const float* Wv = (const float*)d_in[5];
    const float* bv = (const float*)d_in[6];
    const float* Wl = (const float*)d_in[7];
    const float* bl = (const float*)d_in[8];
    float* out = (float*)d_out;

    char* w = (char*)d_ws;
    f16*   xs_h  = (f16*)w;   w += (size_t)M_*D_*2;   // 16.8 MB
    f16*   WvlH  = (f16*)w;   w += (size_t)D_*D_*2;
    f16*   WlH   = (f16*)w;   w += (size_t)D_*D_*2;
    f16*   WvT   = (f16*)w;   w += (size_t)D_*D_*2;
    f16*   WkT   = (f16*)w;   w += (size_t)D_*D_*2;
    f16*   WqT   = (f16*)w;   w += (size_t)D_*D_*2;
    float* Mm    = (float*)w; w += (size_t)D_*D_*4;
    float* MT    = (float*)w; w += (size_t)D_*D_*4;
    float* pXS   = (float*)w; w += (size_t)256*512*4;  // 512 KB
    float* pY    = (float*)w; w += (size_t)256*512*4;  // 512 KB
    float* pS0   = (float*)w; w += 256*4;
    f16*   uH    = (f16*)w;   w += (size_t)B_*D_*2;
    float* hG    = (float*)w; w += (size_t)B_*D_*4;
    float* t1    = (float*)w; w += (size_t)D_*4;
    float* t2    = (float*)w; w += (size_t)D_*4;
    float* bvlG  = (float*)w; w += (size_t)D_*4;
    float* S0G   = (float*)w; w += 4*4;
    float* c1G   = (float*)w; w += 4*4;
    float* c2G   = (float*)w; w += 4*4;
    float* t12   = (float*)w; w += 4;
    if ((size_t)(w - (char*)d_ws) > ws_size) return;  // fail loudly

    prep_tr_kernel<<<512, 256, 0, stream>>>(xs, Wv, Wk, Wq, Wl,
        xs_h, pXS, WvT, WkT, WqT, WlH);
    wmm_kernel<<<dim3(8,8,2), 256, 0, stream>>>(WlH, WvT, WkT, WqT, Wl, bv, bk, bq,
        WvlH, bvlG, Mm, MT, t1, t2, t12);
    mva_kernel<<<33, 256, 0, stream>>>(pXS, nullptr, MT, t1, t2, t12,
        hG, nullptr, c1G, nullptr);
    z_kernel<<<256, 256, 0, stream>>>(xs_h, hG, c1G, pY, pS0);
    mva_kernel<<<33, 256, 0, stream>>>(pY, pS0, Mm, t2, t1, t12,
        nullptr, uH, c2G, S0G);
    vl_gemm<<<dim3(128,4), 256, 0, stream>>>(xs_h, WvlH, bvlG, bl, uH, c2G, S0G, out);
}

// Round 8
// 157.440 us; speedup vs baseline: 1.2666x; 1.2666x over previous
//
#include <hip/hip_runtime.h>
#include <cstdint>

#define B_ 4
#define S_ 4096
#define D_ 512
#define M_ (B_*S_)   // 16384 rows

typedef _Float16 f16;
typedef _Float16 f16x8 __attribute__((ext_vector_type(8)));
typedef _Float16 f16x4 __attribute__((ext_vector_type(4)));
typedef _Float16 f16x2 __attribute__((ext_vector_type(2)));
typedef float    f32x4 __attribute__((ext_vector_type(4)));

typedef __attribute__((address_space(1))) void* as1p;
typedef __attribute__((address_space(3))) void* as3p;

__device__ __forceinline__ void gl2lds16(const void* g, void* l) {
    __builtin_amdgcn_global_load_lds((as1p)g, (as3p)l, 16, 0, 0);
}

union f16pack { f16x8 v8; f16x2 v2[4]; };

// ---------------- prep_tr: blocks 0..255 = xs cast + atomic column sums into xsSum;
//                  blocks 256..511 = weight transpose/cast to f16 ----------------
__global__ __launch_bounds__(256) void prep_tr_kernel(
    const float* __restrict__ xs,
    const float* __restrict__ Wv, const float* __restrict__ Wk,
    const float* __restrict__ Wq, const float* __restrict__ Wl,
    f16* __restrict__ xs_h, float* __restrict__ xsSum,
    f16* __restrict__ WvT, f16* __restrict__ WkT, f16* __restrict__ WqT,
    f16* __restrict__ WlH)
{
    __shared__ float smem[64*68];   // prep: red[4][512] (8KB); tr: tile[64][68] (17.4KB)
    const int t = threadIdx.x;
    if (blockIdx.x < 256) {
        const int blk = blockIdx.x;
        const int w = t >> 6, l = t & 63;
        const int col = l * 8;
        float acc[8] = {0,0,0,0,0,0,0,0};
        for (int c = 0; c < 16; c++) {
            int row = blk*64 + c*4 + w;
            const float4* p = (const float4*)(xs + (size_t)row*512 + col);
            float4 a = p[0], b = p[1];
            f16x8 o;
            o[0]=(f16)a.x; o[1]=(f16)a.y; o[2]=(f16)a.z; o[3]=(f16)a.w;
            o[4]=(f16)b.x; o[5]=(f16)b.y; o[6]=(f16)b.z; o[7]=(f16)b.w;
            *(f16x8*)(xs_h + (size_t)row*512 + col) = o;
            acc[0]+=a.x; acc[1]+=a.y; acc[2]+=a.z; acc[3]+=a.w;
            acc[4]+=b.x; acc[5]+=b.y; acc[6]+=b.z; acc[7]+=b.w;
        }
        #pragma unroll
        for (int q = 0; q < 8; q++) smem[w*512 + col + q] = acc[q];
        __syncthreads();
        const int b = blk >> 6;
        #pragma unroll
        for (int k = 0; k < 2; k++) {
            int c = t + k*256;
            atomicAdd(&xsSum[b*512 + c], smem[c] + smem[512+c] + smem[1024+c] + smem[1536+c]);
        }
        return;
    }
    const int v = blockIdx.x - 256;
    const int z = v >> 6, tile_id = v & 63;
    const int bx = tile_id & 7, by = tile_id >> 3;
    if (z == 3) {    // Wl cast (row-major f16)
        const size_t base = (size_t)tile_id*4096 + t*16;
        const float4* s4 = (const float4*)(Wl + base);
        float4 a0 = s4[0], a1 = s4[1], a2 = s4[2], a3 = s4[3];
        f16x8 o0, o1;
        o0[0]=(f16)a0.x; o0[1]=(f16)a0.y; o0[2]=(f16)a0.z; o0[3]=(f16)a0.w;
        o0[4]=(f16)a1.x; o0[5]=(f16)a1.y; o0[6]=(f16)a1.z; o0[7]=(f16)a1.w;
        o1[0]=(f16)a2.x; o1[1]=(f16)a2.y; o1[2]=(f16)a2.z; o1[3]=(f16)a2.w;
        o1[4]=(f16)a3.x; o1[5]=(f16)a3.y; o1[6]=(f16)a3.z; o1[7]=(f16)a3.w;
        *(f16x8*)(WlH + base)     = o0;
        *(f16x8*)(WlH + base + 8) = o1;
        return;
    }
    // transpose tile (row stride 68 floats = 272 B -> float4 stores at {0,64,128,192} aligned)
    float (*tile)[68] = (float(*)[68])smem;
    const float* src = (z == 0) ? Wv : ((z == 1) ? Wk : Wq);
    f16* dst = (z == 0) ? WvT : ((z == 1) ? WkT : WqT);
    const int i0 = bx*64, j0 = by*64;
    const int r = t >> 2, cpart = (t & 3)*16;
    {
        const float4* s4 = (const float4*)(src + (size_t)(i0 + r)*512 + j0 + cpart);
        float4 a0 = s4[0], a1 = s4[1], a2 = s4[2], a3 = s4[3];
        *(float4*)&tile[r][cpart]    = a0;
        *(float4*)&tile[r][cpart+4]  = a1;
        *(float4*)&tile[r][cpart+8]  = a2;
        *(float4*)&tile[r][cpart+12] = a3;
    }
    __syncthreads();
    const int c = t >> 2, rpart = (t & 3)*16;
    f16x8 o0, o1;
    #pragma unroll
    for (int q = 0; q < 8; q++) o0[q] = (f16)tile[rpart + q][c];
    #pragma unroll
    for (int q = 0; q < 8; q++) o1[q] = (f16)tile[rpart + 8 + q][c];
    *(f16x8*)(dst + (size_t)(j0 + c)*512 + i0 + rpart)     = o0;
    *(f16x8*)(dst + (size_t)(j0 + c)*512 + i0 + rpart + 8) = o1;
}

// ---------------- wmm: MFMA weight GEMMs ----------------
// z==0: Wvl = WlH @ WvT^T (f16 out); y==0: bvl = Wl@bv
// z==1: Mm[j][e] = sum_d Wk[d][j]*Wq[d][e] (A=WkT,B=WqT, fp32 coalesced);
//       x==0: t1 from lB&bk; y==0: t2 from lA&bq; (0,0): t12 = bk.bq
// z==2: MT[e][j] (A=WqT,B=WkT, fp32 coalesced)
__global__ __launch_bounds__(256) void wmm_kernel(
    const f16* __restrict__ WlH, const f16* __restrict__ WvT,
    const f16* __restrict__ WkT, const f16* __restrict__ WqT,
    const float* __restrict__ Wl, const float* __restrict__ bv,
    const float* __restrict__ bk, const float* __restrict__ bq,
    f16* __restrict__ WvlH, float* __restrict__ bvlG,
    float* __restrict__ Mm, float* __restrict__ MT,
    float* __restrict__ t1, float* __restrict__ t2, float* __restrict__ t12)
{
    __shared__ f16 lA[64*32];
    __shared__ f16 lB[64*32];
    const int t = threadIdx.x, z = blockIdx.z;
    const int i0 = blockIdx.x*64, j0 = blockIdx.y*64;
    const int lane = t & 63, wid = t >> 6;
    const int wm = (wid & 1)*32, wn = (wid >> 1)*32;
    const f16* A = (z == 0) ? WlH : ((z == 1) ? WkT : WqT);
    const f16* B = (z == 0) ? WvT : ((z == 1) ? WqT : WkT);
    const int srow = t >> 2, skb = (t & 3) << 4;
    const long aoff = (long)(i0 + srow)*1024 + skb;
    const long boff = (long)(j0 + srow)*1024 + skb;
    const unsigned wbase = (unsigned)wid << 10;
    const bool doT1 = (z == 1) && (blockIdx.x == 0);
    const bool doT2 = (z == 1) && (blockIdx.y == 0);
    const int jj = t >> 2, kq = (t & 3)*8;

    f32x4 acc[2][2] = {};
    float t1a = 0.f, t2a = 0.f;
    const int ael = (wm + (lane & 15))*32 + ((lane >> 4) << 3);
    const int bel = (wn + (lane & 15))*32 + ((lane >> 4) << 3);

    for (int k0 = 0; k0 < 512; k0 += 32) {
        __syncthreads();
        gl2lds16((const char*)A + aoff + k0*2, (char*)lA + wbase);
        gl2lds16((const char*)B + boff + k0*2, (char*)lB + wbase);
        __syncthreads();
        f16x8 af[2], bf[2];
        af[0] = *(const f16x8*)(lA + ael);
        af[1] = *(const f16x8*)(lA + ael + 512);
        bf[0] = *(const f16x8*)(lB + bel);
        bf[1] = *(const f16x8*)(lB + bel + 512);
        #pragma unroll
        for (int i = 0; i < 2; i++)
            #pragma unroll
            for (int j = 0; j < 2; j++)
                acc[i][j] = __builtin_amdgcn_mfma_f32_16x16x32_f16(af[i], bf[j], acc[i][j], 0, 0, 0);
        if (doT1) {
            float4 b0 = *(const float4*)(bk + k0 + kq);
            float4 b1 = *(const float4*)(bk + k0 + kq + 4);
            float bb[8] = {b0.x,b0.y,b0.z,b0.w,b1.x,b1.y,b1.z,b1.w};
            #pragma unroll
            for (int q = 0; q < 8; q++) t1a += (float)lB[jj*32 + kq + q] * bb[q];
        }
        if (doT2) {
            float4 b0 = *(const float4*)(bq + k0 + kq);
            float4 b1 = *(const float4*)(bq + k0 + kq + 4);
            float bb[8] = {b0.x,b0.y,b0.z,b0.w,b1.x,b1.y,b1.z,b1.w};
            #pragma unroll
            for (int q = 0; q < 8; q++) t2a += (float)lA[jj*32 + kq + q] * bb[q];
        }
    }

    const int rb = wm + ((lane >> 4) << 2);
    const int cb = wn + (lane & 15);
    if (z == 0) {
        #pragma unroll
        for (int i = 0; i < 2; i++)
            #pragma unroll
            for (int j = 0; j < 2; j++)
                #pragma unroll
                for (int r = 0; r < 4; r++)
                    WvlH[(size_t)(i0 + rb + i*16 + r)*512 + j0 + cb + j*16] = (f16)acc[i][j][r];
        if (blockIdx.y == 0) {
            int r = t >> 2, part = t & 3;
            const float4* wr = (const float4*)(Wl + (size_t)(i0+r)*512 + part*128);
            const float4* bp = (const float4*)(bv + part*128);
            float s = 0.f;
            #pragma unroll 8
            for (int q = 0; q < 32; q++) {
                float4 wv4 = wr[q], b4 = bp[q];
                s += wv4.x*b4.x + wv4.y*b4.y + wv4.z*b4.z + wv4.w*b4.w;
            }
            s += __shfl_xor(s, 1);
            s += __shfl_xor(s, 2);
            if (part == 0) bvlG[i0 + r] = s;
        }
    } else {
        float* Cout = (z == 1) ? Mm : MT;
        #pragma unroll
        for (int i = 0; i < 2; i++)
            #pragma unroll
            for (int j = 0; j < 2; j++)
                #pragma unroll
                for (int r = 0; r < 4; r++)
                    Cout[(size_t)(i0 + rb + i*16 + r)*512 + j0 + cb + j*16] = acc[i][j][r];
        if (doT1) {
            t1a += __shfl_xor(t1a, 1);
            t1a += __shfl_xor(t1a, 2);
            if ((lane & 3) == 0) t1[j0 + jj] = t1a;
        }
        if (doT2) {
            t2a += __shfl_xor(t2a, 1);
            t2a += __shfl_xor(t2a, 2);
            if ((lane & 3) == 0) t2[i0 + jj] = t2a;
        }
        if (z == 1 && blockIdx.x == 0 && blockIdx.y == 0 && wid == 0) {
            float s = 0.f;
            #pragma unroll
            for (int q = 0; q < 8; q++) s += bk[lane + q*64]*bq[lane + q*64];
            #pragma unroll
            for (int m = 1; m < 64; m <<= 1) s += __shfl_xor(s, m);
            if (lane == 0) *t12 = s;
        }
    }
}

// ---------------- mva: oput[b][j] = W[j,:].vin[b] + beta_b*bias2[j]  (+ f16 copy) ----------------
// block 32: cG[b] = bias3.vin[b] + beta_b * t12
__global__ __launch_bounds__(256) void mva_kernel(const float* __restrict__ W,
    const float* __restrict__ vin, const float* __restrict__ bias2,
    const float* __restrict__ bias3, const float* __restrict__ betaG,
    const float* __restrict__ t12G,
    float* __restrict__ oput, f16* __restrict__ oput_h, float* __restrict__ cG)
{
    const int t = threadIdx.x, w = t >> 6, l = t & 63;
    if (blockIdx.x == 32) {
        const float4* b4 = (const float4*)(bias3 + l*8);
        const float4* v4 = (const float4*)(vin + w*512 + l*8);
        float4 b0 = b4[0], b1 = b4[1], v0 = v4[0], v1 = v4[1];
        float s = b0.x*v0.x + b0.y*v0.y + b0.z*v0.z + b0.w*v0.w
                + b1.x*v1.x + b1.y*v1.y + b1.z*v1.z + b1.w*v1.w;
        #pragma unroll
        for (int m = 1; m < 64; m <<= 1) s += __shfl_xor(s, m);
        if (l == 0) {
            float beta = betaG ? betaG[w] : 4096.0f;
            cG[w] = s + beta * (*t12G);
        }
        return;
    }
    float vb[4][8];
    #pragma unroll
    for (int b = 0; b < 4; b++) {
        float4 p0 = *(const float4*)(vin + b*512 + l*8);
        float4 p1 = *(const float4*)(vin + b*512 + l*8 + 4);
        vb[b][0]=p0.x; vb[b][1]=p0.y; vb[b][2]=p0.z; vb[b][3]=p0.w;
        vb[b][4]=p1.x; vb[b][5]=p1.y; vb[b][6]=p1.z; vb[b][7]=p1.w;
    }
    const int r0 = blockIdx.x*16 + w*4;
    float res[4][4];
    #pragma unroll
    for (int r = 0; r < 4; r++) {
        const float4* wr = (const float4*)(W + (size_t)(r0+r)*512 + l*8);
        float4 a = wr[0], c = wr[1];
        float wv[8] = {a.x,a.y,a.z,a.w,c.x,c.y,c.z,c.w};
        #pragma unroll
        for (int b = 0; b < 4; b++) {
            float s = 0.f;
            #pragma unroll
            for (int q = 0; q < 8; q++) s += wv[q]*vb[b][q];
            res[r][b] = s;
        }
    }
    #pragma unroll
    for (int r = 0; r < 4; r++)
        #pragma unroll
        for (int b = 0; b < 4; b++)
            #pragma unroll
            for (int m = 1; m < 64; m <<= 1) res[r][b] += __shfl_xor(res[r][b], m);
    if (l < 4) {
        const float beta = betaG ? betaG[l] : 4096.0f;
        #pragma unroll
        for (int r = 0; r < 4; r++) {
            float val = res[r][l] + beta*bias2[r0 + r];
            oput[l*512 + r0 + r] = val;
            if (oput_h) oput_h[l*512 + r0 + r] = (f16)val;
        }
    }
}

// ---------------- z: iv = 1/(4096 + (xs.h + c1)/512); atomic y += iv*xs, S0 += iv ----------------
__global__ __launch_bounds__(256) void z_kernel(const f16* __restrict__ xs_h,
    const float* __restrict__ hG, const float* __restrict__ c1G,
    float* __restrict__ yG, float* __restrict__ S0G)
{
    __shared__ float hs[512];
    __shared__ float yred[4][512];
    __shared__ float s0red[4];
    const int blk = blockIdx.x, t = threadIdx.x;
    const int b = blk >> 6, w = t >> 6, l = t & 63;
    hs[t] = hG[b*512 + t]; hs[t+256] = hG[b*512 + t + 256];
    __syncthreads();
    const float c1 = c1G[b];
    float hx[8];
    #pragma unroll
    for (int q = 0; q < 8; q++) hx[q] = hs[l*8+q];
    float yacc[8] = {0,0,0,0,0,0,0,0};
    float s0acc = 0.f;
    for (int it = 0; it < 16; it++) {
        int row = blk*64 + w*16 + it;
        f16x8 v = *(const f16x8*)(xs_h + (size_t)row*512 + l*8);
        float xf[8];
        #pragma unroll
        for (int q = 0; q < 8; q++) xf[q] = (float)v[q];
        float d = 0.f;
        #pragma unroll
        for (int q = 0; q < 8; q++) d += xf[q]*hx[q];
        #pragma unroll
        for (int m = 1; m < 64; m <<= 1) d += __shfl_xor(d, m);
        float z  = 4096.0f + (d + c1)*(1.0f/512.0f);
        float iv = 1.0f/z;
        s0acc += iv;
        #pragma unroll
        for (int q = 0; q < 8; q++) yacc[q] += iv*xf[q];
    }
    #pragma unroll
    for (int q = 0; q < 8; q++) yred[w][l*8+q] = yacc[q];
    if (l == 0) s0red[w] = s0acc;
    __syncthreads();
    #pragma unroll
    for (int k = 0; k < 2; k++) {
        int c = t + k*256;
        atomicAdd(&yG[b*512 + c], yred[0][c]+yred[1][c]+yred[2][c]+yred[3][c]);
    }
    if (t == 0) atomicAdd(&S0G[b], s0red[0]+s0red[1]+s0red[2]+s0red[3]);
}

// ---------------- vl_gemm: out = tanh(rs*(xs@Wvl^T + bvl) + bl), rs fused via v_dot2 ----------------
__global__ __launch_bounds__(256, 2) void vl_gemm(const f16* __restrict__ A,
    const f16* __restrict__ Bt, const float* __restrict__ bvlG,
    const float* __restrict__ blG, const f16* __restrict__ uH,
    const float* __restrict__ c2G, const float* __restrict__ S0G,
    float* __restrict__ out)
{
    constexpr int K = 512;
    __shared__ f16 lA[128*32];
    __shared__ f16 lB[128*32];
    __shared__ float rsbuf[128];
    const int t = threadIdx.x;
    const int m0 = blockIdx.x*128, n0 = blockIdx.y*128;
    const int lane = t & 63, wid = t >> 6;
    const int wm = (wid & 1) << 6, wn = (wid >> 1) << 6;
    const int srow = t >> 2, skb = (t & 3) << 4;
    const long aoff0 = (long)(m0 + srow)*(K*2) + skb;
    const long aoff1 = aoff0 + 64L*(K*2);
    const long boff0 = (long)(n0 + srow)*(K*2) + skb;
    const long boff1 = boff0 + 64L*(K*2);
    char* ldsA = (char*)lA;
    char* ldsB = (char*)lB;
    const unsigned wbase = (unsigned)wid << 10;
    const char* Ab = (const char*)A;
    const char* Bb = (const char*)Bt;

    const int bat = blockIdx.x >> 5;          // 32 m-tiles per batch
    const f16* u = uH + bat*512;
    const int ku = (lane >> 4) << 3;

    f32x4 acc[4][4] = {};
    float racc[4] = {0.f,0.f,0.f,0.f};
    const int ael = (wm + (lane & 15))*32 + ku;
    const int bel = (wn + (lane & 15))*32 + ku;

    for (int k0 = 0; k0 < K; k0 += 32) {
        __syncthreads();
        const long kb = (long)k0*2;
        gl2lds16(Ab + aoff0 + kb, ldsA + wbase);
        gl2lds16(Ab + aoff1 + kb, ldsA + 4096 + wbase);
        gl2lds16(Bb + boff0 + kb, ldsB + wbase);
        gl2lds16(Bb + boff1 + kb, ldsB + 4096 + wbase);
        __syncthreads();
        f16x8 af[4], bf[4];
        #pragma unroll
        for (int i = 0; i < 4; i++) af[i] = *(const f16x8*)(lA + ael + i*512);
        #pragma unroll
        for (int j = 0; j < 4; j++) bf[j] = *(const f16x8*)(lB + bel + j*512);
        f16pack up; up.v8 = *(const f16x8*)(u + k0 + ku);
        #pragma unroll
        for (int i = 0; i < 4; i++) {
            f16pack ap; ap.v8 = af[i];
            #pragma unroll
            for (int q = 0; q < 4; q++)
                racc[i] = __builtin_amdgcn_fdot2(ap.v2[q], up.v2[q], racc[i], false);
        }
        #pragma unroll
        for (int i = 0; i < 4; i++)
            #pragma unroll
            for (int j = 0; j < 4; j++)
                acc[i][j] = __builtin_amdgcn_mfma_f32_16x16x32_f16(af[i], bf[j], acc[i][j], 0, 0, 0);
    }

    #pragma unroll
    for (int i = 0; i < 4; i++) {
        racc[i] += __shfl_xor(racc[i], 16);
        racc[i] += __shfl_xor(racc[i], 32);
    }
    const float S0 = S0G[bat], c2 = c2G[bat];
    if (wid < 2 && lane < 16) {
        #pragma unroll
        for (int i = 0; i < 4; i++)
            rsbuf[wm + i*16 + lane] = S0 + (racc[i] + c2)*(1.0f/512.0f);
    }
    __syncthreads();

    const int crb = m0 + wm + ((lane >> 4) << 2);
    const int ccb = n0 + wn + (lane & 15);
    const int lrb = wm + ((lane >> 4) << 2);
    #pragma unroll
    for (int i = 0; i < 4; i++) {
        float rsv[4];
        #pragma unroll
        for (int r = 0; r < 4; r++) rsv[r] = rsbuf[lrb + i*16 + r];
        #pragma unroll
        for (int j = 0; j < 4; j++) {
            int c = ccb + j*16;
            float bb = bvlG[c], bo = blG[c];
            #pragma unroll
            for (int r = 0; r < 4; r++) {
                float yv = rsv[r]*(acc[i][j][r] + bb) + bo;
                float e2 = __expf(2.0f*yv);
                out[(size_t)(crb + i*16 + r)*512 + c] = 1.0f - 2.0f/(e2 + 1.0f);
            }
        }
    }
}

extern "C" void kernel_launch(void* const* d_in, const int* in_sizes, int n_in,
                              void* d_out, int out_size, void* d_ws, size_t ws_size,
                              hipStream_t stream)
{
    const float* xs = (const float*)d_in[0];
    const float* Wk = (const float*)d_in[1];
    const float* bk = (const float*)d_in[2];
    const float* Wq = (const float*)d_in[3];
    const float* bq = (const float*)d_in[4];
    const float* Wv = (const float*)d_in[5];
    const float* bv = (const float*)d_in[6];
    const float* Wl = (const float*)d_in[7];
    const float* bl = (const float*)d_in[8];
    float* out = (float*)d_out;

    char* w = (char*)d_ws;
    f16*   xs_h = (f16*)w;   w += (size_t)M_*D_*2;   // 16.8 MB
    f16*   WvlH = (f16*)w;   w += (size_t)D_*D_*2;
    f16*   WlH  = (f16*)w;   w += (size_t)D_*D_*2;
    f16*   WvT  = (f16*)w;   w += (size_t)D_*D_*2;
    f16*   WkT  = (f16*)w;   w += (size_t)D_*D_*2;
    f16*   WqT  = (f16*)w;   w += (size_t)D_*D_*2;
    float* Mm   = (float*)w; w += (size_t)D_*D_*4;   // 1 MB
    float* MT   = (float*)w; w += (size_t)D_*D_*4;   // 1 MB
    // zero region: xsSum | yG | S0G contiguous (one async memset)
    float* xsSum= (float*)w; w += (size_t)B_*D_*4;
    float* yG   = (float*)w; w += (size_t)B_*D_*4;
    float* S0G  = (float*)w; w += 4*4;
    f16*   uH   = (f16*)w;   w += (size_t)B_*D_*2;
    float* hG   = (float*)w; w += (size_t)B_*D_*4;
    float* uG   = (float*)w; w += (size_t)B_*D_*4;
    float* t1   = (float*)w; w += (size_t)D_*4;
    float* t2   = (float*)w; w += (size_t)D_*4;
    float* bvlG = (float*)w; w += (size_t)D_*4;
    float* c1G  = (float*)w; w += 4*4;
    float* c2G  = (float*)w; w += 4*4;
    float* t12  = (float*)w; w += 4;
    if ((size_t)(w - (char*)d_ws) > ws_size) return;  // fail loudly

    hipMemsetAsync(xsSum, 0, (2*B_*D_ + 4)*sizeof(float), stream);
    prep_tr_kernel<<<512, 256, 0, stream>>>(xs, Wv, Wk, Wq, Wl,
        xs_h, xsSum, WvT, WkT, WqT, WlH);
    wmm_kernel<<<dim3(8,8,3), 256, 0, stream>>>(WlH, WvT, WkT, WqT, Wl, bv, bk, bq,
        WvlH, bvlG, Mm, MT, t1, t2, t12);
    mva_kernel<<<33, 256, 0, stream>>>(MT, xsSum, t1, t2, nullptr, t12, hG, nullptr, c1G);
    z_kernel<<<256, 256, 0, stream>>>(xs_h, hG, c1G, yG, S0G);
    mva_kernel<<<33, 256, 0, stream>>>(Mm, yG, t2, t1, S0G, t12, uG, uH, c2G);
    vl_gemm<<<dim3(128,4), 256, 0, stream>>>(xs_h, WvlH, bvlG, bl, uH, c2G, S0G, out);
}